// Round 7
// baseline (540.525 us; speedup 1.0000x reference)
//
#include <hip/hip_runtime.h>

#define L1_BINS 4096          // top 12 bits of 22-bit fixed-point key
#define L1_UINTS 2048         // packed pairs (16-bit counts)
#define L2_BINS 1024          // low 10 bits
#define KEY_MAX 4194303u      // 2^22 - 1
#define NH2_BLOCKS 2048       // 8 blocks/CU (8KB LDS) -> 100% wave occupancy
#define NMG_BLOCKS 256
#define NREF_BLOCKS 2048
#define NBIN_BLOCKS 1024

struct Ranks { unsigned int r[32]; };
struct Fracs { float f[16]; };

__device__ __forceinline__ unsigned int wave_iscan(unsigned int s, int lane) {
  unsigned int inc = s;
#pragma unroll
  for (int d = 1; d < 64; d <<= 1) {
    unsigned int u = __shfl_up(inc, d);
    if (lane >= d) inc += u;
  }
  return inc;
}

// ---------------- Kernel 1: H2 + err -> packed keys + per-block L1 hist ----
// 4 lanes/row coalesced loads; 8KB packed LDS hist; plain-store flush.
__global__ __launch_bounds__(256) void k_h2(const float* __restrict__ logits,
                                            const int* __restrict__ labels,
                                            unsigned int* __restrict__ keys,
                                            unsigned int* __restrict__ histg,
                                            unsigned int* __restrict__ dones,
                                            int n) {
  __shared__ unsigned int lh[L1_UINTS];
  for (int i = threadIdx.x; i < L1_UINTS; i += 256) lh[i] = 0u;
  if (blockIdx.x == 0 && threadIdx.x < 3) dones[threadIdx.x] = 0u;
  __syncthreads();
  int tid = blockIdx.x * 256 + threadIdx.x;
  int sub = tid & 3;
  int group = tid >> 2;
  int ngroups = (gridDim.x * 256) >> 2;
  for (int row = group; row < n; row += ngroups) {
    float4 v = reinterpret_cast<const float4*>(logits)[(size_t)row * 4 + sub];
    float m = v.x; int a = 0;
    if (v.y > m) { m = v.y; a = 1; }
    if (v.z > m) { m = v.z; a = 2; }
    if (v.w > m) { m = v.w; a = 3; }
    int gidx = sub * 4 + a;
#pragma unroll
    for (int mask = 1; mask <= 2; mask <<= 1) {
      float om = __shfl_xor(m, mask);
      int oi = __shfl_xor(gidx, mask);
      if (om > m || (om == m && oi < gidx)) { m = om; gidx = oi; }
    }
    float e0 = __expf(v.x - m), e1 = __expf(v.y - m);
    float e2 = __expf(v.z - m), e3 = __expf(v.w - m);
    float Z = e0 + e1 + e2 + e3;
    float S2 = e0 * e0 + e1 * e1 + e2 * e2 + e3 * e3;
#pragma unroll
    for (int mask = 1; mask <= 2; mask <<= 1) {
      Z += __shfl_xor(Z, mask);
      S2 += __shfl_xor(S2, mask);
    }
    if (sub == 0) {
      float r = S2 / (Z * Z) + 1e-12f;
      float h2 = -__log2f(r);
      int ki = (int)(h2 * 1048576.0f);
      unsigned int key = (unsigned int)min(max(ki, 0), (int)KEY_MAX);
      keys[row] = key | ((gidx != labels[row]) ? 0x80000000u : 0u);
      // L1 bin = key>>10 (12b); packed uint = bin>>1, half = bin&1
      atomicAdd(&lh[key >> 11], ((key >> 10) & 1u) ? 65536u : 1u);
    }
  }
  __syncthreads();
  unsigned int* dst = histg + (size_t)blockIdx.x * L1_UINTS;
  for (int i = threadIdx.x; i < L1_UINTS; i += 256) dst[i] = lh[i];
}

// ---------------- Kernel 2: merge hists; last block does select-L1 ---------
__global__ __launch_bounds__(256) void k_merge(const unsigned int* __restrict__ histg,
                                               unsigned int* __restrict__ merged,
                                               unsigned int* __restrict__ hist2,
                                               unsigned int* __restrict__ dones,
                                               unsigned int* __restrict__ selpfx,
                                               unsigned int* __restrict__ selrank,
                                               Ranks rk) {
  __shared__ unsigned int slo[32][9], shi[32][9];
  __shared__ unsigned int is_last;
  // zero hist2 slice (32*1024 uints / 256 blocks = 128 per block)
  for (int i = threadIdx.x; i < 128; i += 256)
    hist2[blockIdx.x * 128 + i] = 0u;
  int col0 = blockIdx.x * 8;          // 8 pair-cols per block (2048/256)
  int c = threadIdx.x & 7;
  int rg = threadIdx.x >> 3;          // 32 row groups
  unsigned int alo = 0, ahi = 0;
  for (int r = rg; r < NH2_BLOCKS; r += 32) {
    unsigned int v = histg[(size_t)r * L1_UINTS + col0 + c];
    alo += v & 0xFFFFu;
    ahi += v >> 16;
  }
  slo[rg][c] = alo;
  shi[rg][c] = ahi;
  __syncthreads();
  if (threadIdx.x < 8) {
    unsigned int lo = 0, hi = 0;
#pragma unroll
    for (int g = 0; g < 32; ++g) { lo += slo[g][threadIdx.x]; hi += shi[g][threadIdx.x]; }
    int pc = col0 + threadIdx.x;
    merged[2 * pc] = lo;
    merged[2 * pc + 1] = hi;
  }
  __threadfence();
  __syncthreads();
  if (threadIdx.x == 0)
    is_last = (atomicAdd(&dones[0], 1u) == (unsigned int)gridDim.x - 1u) ? 1u : 0u;
  __syncthreads();
  if (!is_last) return;
  __threadfence();
  // ---- select-L1: 4 waves x 8 queries; two-level 64-way scan over 4096 ----
  int wid = threadIdx.x >> 6, lane = threadIdx.x & 63;
  for (int j = wid; j < 32; j += 4) {
    unsigned int rem = rk.r[j];
    const unsigned int* mp = merged + lane * 64;
    unsigned int s = 0;
#pragma unroll 8
    for (int t = 0; t < 64; ++t) s += mp[t];
    unsigned int inc = wave_iscan(s, lane);
    unsigned int ex = inc - s;
    bool own = (rem >= ex) && (rem < ex + s);
    int src = __ffsll((long long)__ballot(own)) - 1;
    rem -= __shfl(ex, src);
    int base = src * 64;
    unsigned int v2 = merged[base + lane];
    unsigned int inc2 = wave_iscan(v2, lane);
    unsigned int ex2 = inc2 - v2;
    bool own2 = (rem >= ex2) && (rem < ex2 + v2);
    int s2 = __ffsll((long long)__ballot(own2)) - 1;
    unsigned int ex2s = __shfl(ex2, s2);
    if (lane == 0) {
      selpfx[j] = (unsigned int)(base + s2);
      selrank[j] = rem - ex2s;
    }
  }
}

// ---------------- Kernel 3: refine (low 10 bits); last block select-L2 -----
__global__ __launch_bounds__(256) void k_refine(const unsigned int* __restrict__ keys,
                                                const unsigned int* __restrict__ selpfx,
                                                unsigned int* __restrict__ hist2,
                                                unsigned int* __restrict__ dones,
                                                unsigned int* __restrict__ selrank,
                                                unsigned int* __restrict__ vout,
                                                int n) {
  __shared__ unsigned int sp[32];
  __shared__ unsigned int is_last;
  if (threadIdx.x < 32) sp[threadIdx.x] = selpfx[threadIdx.x];
  __syncthreads();
  int stride = gridDim.x * blockDim.x;
  for (int i = blockIdx.x * blockDim.x + threadIdx.x; i < n; i += stride) {
    unsigned int key = keys[i] & KEY_MAX;
    unsigned int hi = key >> 10;
    unsigned int sb = key & (L2_BINS - 1);
#pragma unroll
    for (int jj = 0; jj < 32; ++jj)
      if (hi == sp[jj]) atomicAdd(&hist2[jj * L2_BINS + (int)sb], 1u);
  }
  __threadfence();
  __syncthreads();
  if (threadIdx.x == 0)
    is_last = (atomicAdd(&dones[1], 1u) == (unsigned int)gridDim.x - 1u) ? 1u : 0u;
  __syncthreads();
  if (!is_last) return;
  __threadfence();
  // ---- select-L2: 4 waves x 8 queries over 1024 bins each ----
  int wid = threadIdx.x >> 6, lane = threadIdx.x & 63;
  for (int j = wid; j < 32; j += 4) {
    unsigned int rem = selrank[j];
    const unsigned int* h = hist2 + j * L2_BINS;
    unsigned int s = 0;
#pragma unroll
    for (int t = 0; t < 16; ++t) s += h[lane * 16 + t];
    unsigned int inc = wave_iscan(s, lane);
    unsigned int ex = inc - s;
    bool own = (rem >= ex) && (rem < ex + s);
    int src = __ffsll((long long)__ballot(own)) - 1;
    rem -= __shfl(ex, src);
    unsigned int v2 = (lane < 16) ? h[src * 16 + lane] : 0u;
    unsigned int inc2 = wave_iscan(v2, lane);
    unsigned int ex2 = inc2 - v2;
    bool own2 = (lane < 16) && (rem >= ex2) && (rem < ex2 + v2);
    int s2 = __ffsll((long long)__ballot(own2)) - 1;
    if (lane == 0)
      vout[j] = (sp[j] << 10) | (unsigned int)(src * 16 + s2);  // 22-bit key
  }
}

// ---------------- Kernel 4: binning + fused final reduction ---------------
__global__ __launch_bounds__(256) void k_bin(const unsigned int* __restrict__ keys,
                                             const unsigned int* __restrict__ vp,
                                             float* __restrict__ partials,
                                             unsigned int* __restrict__ dones,
                                             float* __restrict__ out, int n,
                                             Fracs fr) {
  __shared__ float sedge[16];
  __shared__ float swacc[4][48];
  __shared__ unsigned int is_last;
  if (threadIdx.x < 16) {
    int i = threadIdx.x;
    unsigned int klo = vp[2 * i];
    unsigned int khi = vp[2 * i + 1];
    float lo = (float)(klo + 1u) * 0x1p-20f;   // bin upper boundary (exact)
    float hi = (float)(khi + 1u) * 0x1p-20f;
    float f = fr.f[i];
    float e = lo * (1.0f - f) + hi * f;
    if (i == 15) e += 1e-6f;
    sedge[i] = e;
  }
  __syncthreads();
  float e[16];
#pragma unroll
  for (int j = 0; j < 16; ++j) e[j] = sedge[j];
  float cnt[15], sH[15], sE[15];
#pragma unroll
  for (int b = 0; b < 15; ++b) { cnt[b] = 0.f; sH[b] = 0.f; sE[b] = 0.f; }
  int stride = gridDim.x * blockDim.x;
  for (int i = blockIdx.x * blockDim.x + threadIdx.x; i < n; i += stride) {
    unsigned int kp = keys[i];
    float h = ((float)(kp & KEY_MAX) + 0.5f) * 0x1p-20f;
    float er = (kp & 0x80000000u) ? 1.0f : 0.0f;
    int less = 0;
#pragma unroll
    for (int j = 0; j < 16; ++j) less += (h > e[j]) ? 1 : 0;
    int bin = less - 1;  // valid bins 0..14
#pragma unroll
    for (int b = 0; b < 15; ++b) {
      bool mm = (bin == b);
      cnt[b] += mm ? 1.f : 0.f;
      sH[b] += mm ? h : 0.f;
      sE[b] += mm ? er : 0.f;
    }
  }
  int wid = threadIdx.x >> 6;
  int lane = threadIdx.x & 63;
#pragma unroll
  for (int b = 0; b < 15; ++b) {
    float c = cnt[b], a = sH[b], s = sE[b];
    for (int off = 32; off > 0; off >>= 1) {
      c += __shfl_xor(c, off);
      a += __shfl_xor(a, off);
      s += __shfl_xor(s, off);
    }
    if (lane == 0) {
      swacc[wid][b] = c;
      swacc[wid][15 + b] = a;
      swacc[wid][30 + b] = s;
    }
  }
  __syncthreads();
  if (threadIdx.x < 45) {
    int v = threadIdx.x;
    float s = swacc[0][v] + swacc[1][v] + swacc[2][v] + swacc[3][v];
    partials[v * NBIN_BLOCKS + blockIdx.x] = s;
  }
  __threadfence();
  __syncthreads();
  if (threadIdx.x == 0)
    is_last = (atomicAdd(&dones[2], 1u) == (unsigned int)gridDim.x - 1u) ? 1u : 0u;
  __syncthreads();
  if (is_last && threadIdx.x < 64) {
    __threadfence();
    __shared__ float sacc[45];
    int l = threadIdx.x;
    for (int v = 0; v < 45; ++v) {
      float s = 0.f;
      for (int b = l; b < NBIN_BLOCKS; b += 64) s += partials[v * NBIN_BLOCKS + b];
      for (int off = 32; off > 0; off >>= 1) s += __shfl_xor(s, off);
      if (l == 0) sacc[v] = s;
    }
    __builtin_amdgcn_s_barrier();  // single wave
    float g = 0.f;
    if (l < 15) {
      float c = sacc[l], sh = sacc[15 + l], se = sacc[30 + l];
      float safe = fmaxf(c, 1.f);
      float u = sh / safe, eb = se / safe;
      float inner = 2.0f * exp2f(-u) - 1.0f;
      float s = (inner > 0.f) ? sqrtf(inner) : 0.f;
      float risk = 0.5f * (1.0f - s);
      g = (c > 0.f) ? fabsf(eb - risk) : 0.f;
    }
    for (int off = 32; off > 0; off >>= 1) g += __shfl_xor(g, off);
    if (l == 0) out[0] = g * (1.0f / 15.0f);
  }
}

extern "C" void kernel_launch(void* const* d_in, const int* in_sizes, int n_in,
                              void* d_out, int out_size, void* d_ws, size_t ws_size,
                              hipStream_t stream) {
  const float* logits = (const float*)d_in[0];
  const int* labels = (const int*)d_in[1];
  float* out = (float*)d_out;
  int n = in_sizes[1];  // labels count = number of rows

  char* ws = (char*)d_ws;
  size_t offKeys = 0;                                             // n*4 = 16MB
  size_t offHg = (size_t)n * 4;                                   // 2048*2048*4 = 16MB
  size_t offMerged = offHg + (size_t)NH2_BLOCKS * L1_UINTS * 4;   // 4096*4
  size_t offH2b = offMerged + (size_t)L1_BINS * 4;                // 32*1024*4 = 128KB
  size_t offDone = offH2b + (size_t)32 * L2_BINS * 4;             // 16B
  size_t offSelP = offDone + 16;                                  // 32*4
  size_t offSelR = offSelP + 128;                                 // 32*4
  size_t offV = offSelR + 128;                                    // 32*4
  size_t offPart = (offV + 128 + 255) & ~(size_t)255;             // 45*NBIN_BLOCKS*4

  unsigned int* keys = (unsigned int*)(ws + offKeys);
  unsigned int* histg = (unsigned int*)(ws + offHg);
  unsigned int* merged = (unsigned int*)(ws + offMerged);
  unsigned int* hist2 = (unsigned int*)(ws + offH2b);
  unsigned int* dones = (unsigned int*)(ws + offDone);
  unsigned int* selp = (unsigned int*)(ws + offSelP);
  unsigned int* selr = (unsigned int*)(ws + offSelR);
  unsigned int* vp = (unsigned int*)(ws + offV);
  float* part = (float*)(ws + offPart);

  // host-side quantile positions (f32, matching jnp.linspace/quantile math)
  Ranks rk;
  Fracs fr;
  float nm1 = (float)(n - 1);
  for (int i = 0; i < 16; ++i) {
    float q = (i == 15) ? 1.0f : (float)i * (1.0f / 15.0f);
    float idxf = q * nm1;
    float flo = floorf(idxf);
    unsigned int klo = (unsigned int)flo;
    unsigned int khi = (unsigned int)ceilf(idxf);
    unsigned int maxi = (unsigned int)(n - 1);
    if (klo > maxi) klo = maxi;
    if (khi > maxi) khi = maxi;
    rk.r[2 * i] = klo;
    rk.r[2 * i + 1] = khi;
    fr.f[i] = idxf - flo;
  }

  // 1) keys + per-block L1 hists (also zeroes done counters)
  k_h2<<<NH2_BLOCKS, 256, 0, stream>>>(logits, labels, keys, histg, dones, n);
  // 2) merge hists; zero hist2; last block -> select L1 (12 bits)
  k_merge<<<NMG_BLOCKS, 256, 0, stream>>>(histg, merged, hist2, dones, selp, selr, rk);
  // 3) refine low 10 bits; last block -> select L2 -> final keys
  k_refine<<<NREF_BLOCKS, 256, 0, stream>>>(keys, selp, hist2, dones, selr, vp, n);
  // 4) binning + fused final reduction
  k_bin<<<NBIN_BLOCKS, 256, 0, stream>>>(keys, vp, part, dones, out, n, fr);

  (void)n_in; (void)out_size; (void)ws_size;
}